// Round 1
// baseline (142.999 us; speedup 1.0000x reference)
//
#include <hip/hip_runtime.h>

#define RES 128
#define NCELLS (RES * RES * RES)        // 2097152
#define CASC 4
#define GRID_TOTAL (CASC * NCELLS)      // 8388608
#define NBYTES (GRID_TOTAL / 8)         // 1048576

// inverse of instant-ngp expand_bits: gather every 3rd bit
__device__ __forceinline__ unsigned compact3(unsigned v) {
    v &= 0x49249249u;
    v = (v | (v >> 2))  & 0xC30C30C3u;
    v = (v | (v >> 4))  & 0x0F00F00Fu;
    v = (v | (v >> 8))  & 0xFF0000FFu;
    v = (v | (v >> 16)) & 0x3FFu;
    return v;
}

// One thread per morton index m; handles all 4 cascades.
// Coalesced: density_grid read, new_grid write. Scattered (morton-local): jitter read.
__global__ __launch_bounds__(256) void dg_main(
    const float* __restrict__ dgrid,   // [CASC, NCELLS]
    const float* __restrict__ jit,     // [CASC, NCELLS, 3]
    const float* __restrict__ W1,      // [3,32]
    const float* __restrict__ b1,      // [32]
    const float* __restrict__ W2,      // [32]
    const float* __restrict__ b2,      // [1]
    float* __restrict__ out,           // [CASC, NCELLS]
    double* __restrict__ sum_ws)
{
    const int m = blockIdx.x * 256 + threadIdx.x;
    const unsigned x = compact3((unsigned)m);
    const unsigned y = compact3((unsigned)m >> 1);
    const unsigned z = compact3((unsigned)m >> 2);
    const int c = (int)((x << 14) | (y << 7) | z);   // linear cell index

    const float cx = (float)x, cy = (float)y, cz = (float)z;
    const float bb2 = b2[0];

    double lsum = 0.0;

    #pragma unroll
    for (int lvl = 0; lvl < CASC; ++lvl) {
        const float scale = (float)(1 << lvl);
        const float* jp = jit + ((size_t)lvl * NCELLS + (size_t)c) * 3;
        const float jx = jp[0], jy = jp[1], jz = jp[2];
        // x = ((cf + jitter)/128 - 0.5) * 2^lvl   (all steps exact or same-rounded as ref)
        const float px = ((cx + jx) * (1.0f / 128.0f) - 0.5f) * scale;
        const float py = ((cy + jy) * (1.0f / 128.0f) - 0.5f) * scale;
        const float pz = ((cz + jz) * (1.0f / 128.0f) - 0.5f) * scale;

        float acc = bb2;
        #pragma unroll
        for (int j = 0; j < 32; ++j) {
            float a = b1[j];
            a = fmaf(px, W1[j], a);
            a = fmaf(py, W1[32 + j], a);
            a = fmaf(pz, W1[64 + j], a);
            a = fmaxf(a, 0.0f);              // relu
            acc = fmaf(a, W2[j], acc);
        }
        // softplus(acc) = max(acc,0) + log1p(exp(-|acc|))   (jax.nn.softplus / logaddexp form)
        const float d = fmaxf(acc, 0.0f) + log1pf(expf(-fabsf(acc)));

        const float g = dgrid[(size_t)lvl * NCELLS + m];
        const float nv = (g >= 0.0f && d >= 0.0f) ? fmaxf(g * 0.95f, d) : g;
        out[(size_t)lvl * NCELLS + m] = nv;
        lsum += (double)nv;
    }

    // block reduction (f64) then one atomicAdd per block
    __shared__ double sdata[256];
    sdata[threadIdx.x] = lsum;
    __syncthreads();
    #pragma unroll
    for (int s = 128; s > 0; s >>= 1) {
        if (threadIdx.x < s) sdata[threadIdx.x] += sdata[threadIdx.x + s];
        __syncthreads();
    }
    if (threadIdx.x == 0) atomicAdd(sum_ws, sdata[0]);
}

__global__ void dg_finalize(const double* __restrict__ sum_ws,
                            float* __restrict__ out,
                            float* __restrict__ thr_ws)
{
    const double mean = *sum_ws / (double)GRID_TOTAL;
    const float mf = (float)mean;
    out[GRID_TOTAL] = mf;                 // mean_density output
    *thr_ws = fminf(mf, 2.0f);            // thresh for bitfield pass
}

// One thread per output byte: read 8 consecutive grid floats, pack bits, emit as float.
__global__ __launch_bounds__(256) void dg_bitfield(
    const float* __restrict__ grid,
    const float* __restrict__ thr_ws,
    float* __restrict__ outb)
{
    const int i = blockIdx.x * 256 + threadIdx.x;
    const float t = *thr_ws;
    const float4* p = (const float4*)(grid + (size_t)i * 8);
    const float4 a = p[0];
    const float4 b = p[1];
    int v = 0;
    v |= (a.x > t) ? 1   : 0;
    v |= (a.y > t) ? 2   : 0;
    v |= (a.z > t) ? 4   : 0;
    v |= (a.w > t) ? 8   : 0;
    v |= (b.x > t) ? 16  : 0;
    v |= (b.y > t) ? 32  : 0;
    v |= (b.z > t) ? 64  : 0;
    v |= (b.w > t) ? 128 : 0;
    outb[i] = (float)v;
}

extern "C" void kernel_launch(void* const* d_in, const int* in_sizes, int n_in,
                              void* d_out, int out_size, void* d_ws, size_t ws_size,
                              hipStream_t stream) {
    const float* dgrid = (const float*)d_in[0];
    const float* jit   = (const float*)d_in[1];
    const float* W1    = (const float*)d_in[2];
    const float* b1    = (const float*)d_in[3];
    const float* W2    = (const float*)d_in[4];
    const float* b2    = (const float*)d_in[5];

    float* out = (float*)d_out;
    double* sum_ws = (double*)d_ws;
    float* thr_ws = (float*)((char*)d_ws + 8);

    hipMemsetAsync(d_ws, 0, 8, stream);   // zero the f64 accumulator (capture-safe)

    dg_main<<<NCELLS / 256, 256, 0, stream>>>(dgrid, jit, W1, b1, W2, b2, out, sum_ws);
    dg_finalize<<<1, 1, 0, stream>>>(sum_ws, out, thr_ws);
    dg_bitfield<<<NBYTES / 256, 256, 0, stream>>>(out, thr_ws, out + GRID_TOTAL + 1);
}

// Round 5
// 142.980 us; speedup vs baseline: 1.0001x; 1.0001x over previous
//
#include <hip/hip_runtime.h>

#define RES 128
#define NCELLS (RES * RES * RES)        // 2097152
#define CASC 4
#define GRID_TOTAL (CASC * NCELLS)      // 8388608
#define NBYTES (GRID_TOTAL / 8)         // 1048576

// inverse of instant-ngp expand_bits: gather every 3rd bit
__device__ __forceinline__ unsigned compact3(unsigned v) {
    v &= 0x49249249u;
    v = (v | (v >> 2))  & 0xC30C30C3u;
    v = (v | (v >> 4))  & 0x0F00F00Fu;
    v = (v | (v >> 8))  & 0xFF0000FFu;
    v = (v | (v >> 16)) & 0x3FFu;
    return v;
}

// One thread per morton index m; handles all 4 cascades.
// Coalesced: density_grid read, new_grid write. Scattered (morton-local): jitter read.
__global__ __launch_bounds__(256) void dg_main(
    const float* __restrict__ dgrid,   // [CASC, NCELLS]
    const float* __restrict__ jit,     // [CASC, NCELLS, 3]
    const float* __restrict__ W1,      // [3,32]
    const float* __restrict__ b1,      // [32]
    const float* __restrict__ W2,      // [32]
    const float* __restrict__ b2,      // [1]
    float* __restrict__ out,           // [CASC, NCELLS]
    double* __restrict__ sum_ws)
{
    const int m = blockIdx.x * 256 + threadIdx.x;
    const unsigned x = compact3((unsigned)m);
    const unsigned y = compact3((unsigned)m >> 1);
    const unsigned z = compact3((unsigned)m >> 2);
    const int c = (int)((x << 14) | (y << 7) | z);   // linear cell index

    const float cx = (float)x, cy = (float)y, cz = (float)z;
    const float bb2 = b2[0];

    double lsum = 0.0;

    #pragma unroll
    for (int lvl = 0; lvl < CASC; ++lvl) {
        const float scale = (float)(1 << lvl);
        const float* jp = jit + ((size_t)lvl * NCELLS + (size_t)c) * 3;
        const float jx = jp[0], jy = jp[1], jz = jp[2];
        // x = ((cf + jitter)/128 - 0.5) * 2^lvl   (all steps exact or same-rounded as ref)
        const float px = ((cx + jx) * (1.0f / 128.0f) - 0.5f) * scale;
        const float py = ((cy + jy) * (1.0f / 128.0f) - 0.5f) * scale;
        const float pz = ((cz + jz) * (1.0f / 128.0f) - 0.5f) * scale;

        float acc = bb2;
        #pragma unroll
        for (int j = 0; j < 32; ++j) {
            float a = b1[j];
            a = fmaf(px, W1[j], a);
            a = fmaf(py, W1[32 + j], a);
            a = fmaf(pz, W1[64 + j], a);
            a = fmaxf(a, 0.0f);              // relu
            acc = fmaf(a, W2[j], acc);
        }
        // softplus(acc) = max(acc,0) + log1p(exp(-|acc|))   (jax.nn.softplus / logaddexp form)
        const float d = fmaxf(acc, 0.0f) + log1pf(expf(-fabsf(acc)));

        const float g = dgrid[(size_t)lvl * NCELLS + m];
        const float nv = (g >= 0.0f && d >= 0.0f) ? fmaxf(g * 0.95f, d) : g;
        out[(size_t)lvl * NCELLS + m] = nv;
        lsum += (double)nv;
    }

    // block reduction (f64) then one atomicAdd per block
    __shared__ double sdata[256];
    sdata[threadIdx.x] = lsum;
    __syncthreads();
    #pragma unroll
    for (int s = 128; s > 0; s >>= 1) {
        if (threadIdx.x < s) sdata[threadIdx.x] += sdata[threadIdx.x + s];
        __syncthreads();
    }
    if (threadIdx.x == 0) atomicAdd(sum_ws, sdata[0]);
}

__global__ void dg_finalize(const double* __restrict__ sum_ws,
                            float* __restrict__ out,
                            float* __restrict__ thr_ws)
{
    const double mean = *sum_ws / (double)GRID_TOTAL;
    const float mf = (float)mean;
    out[GRID_TOTAL] = mf;                 // mean_density output
    *thr_ws = fminf(mf, 2.0f);            // thresh for bitfield pass
}

// One thread per output byte: read 8 consecutive grid floats, pack bits, emit as float.
__global__ __launch_bounds__(256) void dg_bitfield(
    const float* __restrict__ grid,
    const float* __restrict__ thr_ws,
    float* __restrict__ outb)
{
    const int i = blockIdx.x * 256 + threadIdx.x;
    const float t = *thr_ws;
    const float4* p = (const float4*)(grid + (size_t)i * 8);
    const float4 a = p[0];
    const float4 b = p[1];
    int v = 0;
    v |= (a.x > t) ? 1   : 0;
    v |= (a.y > t) ? 2   : 0;
    v |= (a.z > t) ? 4   : 0;
    v |= (a.w > t) ? 8   : 0;
    v |= (b.x > t) ? 16  : 0;
    v |= (b.y > t) ? 32  : 0;
    v |= (b.z > t) ? 64  : 0;
    v |= (b.w > t) ? 128 : 0;
    outb[i] = (float)v;
}

extern "C" void kernel_launch(void* const* d_in, const int* in_sizes, int n_in,
                              void* d_out, int out_size, void* d_ws, size_t ws_size,
                              hipStream_t stream) {
    const float* dgrid = (const float*)d_in[0];
    const float* jit   = (const float*)d_in[1];
    const float* W1    = (const float*)d_in[2];
    const float* b1    = (const float*)d_in[3];
    const float* W2    = (const float*)d_in[4];
    const float* b2    = (const float*)d_in[5];

    float* out = (float*)d_out;
    double* sum_ws = (double*)d_ws;
    float* thr_ws = (float*)((char*)d_ws + 8);

    hipMemsetAsync(d_ws, 0, 8, stream);   // zero the f64 accumulator (capture-safe)

    dg_main<<<NCELLS / 256, 256, 0, stream>>>(dgrid, jit, W1, b1, W2, b2, out, sum_ws);
    dg_finalize<<<1, 1, 0, stream>>>(sum_ws, out, thr_ws);
    dg_bitfield<<<NBYTES / 256, 256, 0, stream>>>(out, thr_ws, out + GRID_TOTAL + 1);
}